// Round 12
// baseline (34.891 us; speedup 1.0000x reference)
//
#include <hip/hip_runtime.h>
#include <math.h>

#define LOG2E 1.4426950408889634f
#define LN2   0.6931471805599453f
#define MAGIC 0x5EED1234u

#if __has_builtin(__builtin_amdgcn_exp2f)
#define EXP2(x) __builtin_amdgcn_exp2f(x)
#else
#define EXP2(x) exp2f(x)
#endif
#if __has_builtin(__builtin_amdgcn_logf)
#define LOG2(x) __builtin_amdgcn_logf(x)
#else
#define LOG2(x) log2f(x)
#endif

// R10 body byte-identical (validated absmax 0.0). R11 = DIAGNOSTIC PROBE:
// the SAME kernel is dispatched TWICE in the graph. Dispatch 2 recomputes and
// rewrites byte-identical values (deterministic; word-atomic identical-value
// races are benign; MAGIC flags only short-circuit the merger wait).
// Measurement: wall(2x) - wall(1x) = true kernel dur + node gap.
// Floor model predicts ~20-24us total; real-body model predicts ~36-40us.

__global__ __launch_bounds__(256) void k_fused(
    const float* __restrict__ yr, const float* __restrict__ yi,
    const float* __restrict__ hr, const float* __restrict__ hi,
    const float* __restrict__ sr, const float* __restrict__ si,
    const float* __restrict__ vr, const float* __restrict__ vi,
    unsigned* __restrict__ flags, float* __restrict__ pairs,
    float* __restrict__ out)
{
    __shared__ float sL[8][8][2];
    __shared__ float sDinv[8];
    __shared__ float lyw[8][2];
    __shared__ float lhw[8][4][2];     // whitened h [m][k]
    __shared__ float ptr_[16], pti_[16];
    __shared__ float gdiag[4];         // g_aa (real)
    __shared__ float gr2[6], gi2[6];   // g_ab for pairs (01,02,03,12,13,23)
    __shared__ float wr_[4], wi_[4];   // w_a = sum_m conj(hw[m,a]) yw[m]
    __shared__ float u2s;              // LOG2E * |yw|^2
    __shared__ float G2[4][16];        // LOG2E * G_a[v]
    __shared__ float P2[6][16][16];    // 2*LOG2E * P_ab[va][vb]
    __shared__ float xbuf[16][256];    // [d1=s][c]
    __shared__ float pmax[256];
    __shared__ float cm[16][17];       // [s][cluster] maxes, reused for j1 sums
    __shared__ float m1b[16], m2b[16], m3b[16], s2b[16];
    __shared__ float part2[256], part3[256];

    const int t = threadIdx.x;
    const int b = blockIdx.x >> 3, g = blockIdx.x & 7;
    const int i2 = t >> 4, i3 = t & 15;

    if (t < 16) { ptr_[t] = vr[(t << 12) * 4]; pti_[t] = vi[(t << 12) * 4]; }

    // ---------------- wave 0: whiten (validated R2..R10) ----------------
    if (t < 64) {
        const int lane = t;
        float ar_[8] = {}, ai_[8] = {}, Lr_[8] = {}, Li_[8] = {};
        if (lane < 8) {
#pragma unroll
            for (int k = 0; k < 8; ++k) {
                ar_[k] = sr[b * 64 + lane * 8 + k];
                ai_[k] = si[b * 64 + lane * 8 + k];
            }
        }
        float inv = 0.f;
#pragma unroll
        for (int j = 0; j < 8; ++j) {
            if (lane == j) {
                float d = ar_[j];
#pragma unroll
                for (int k = 0; k < 8; ++k) if (k < j) d -= Lr_[k]*Lr_[k] + Li_[k]*Li_[k];
                float ld = sqrtf(d);
                Lr_[j] = ld; Li_[j] = 0.f;
                inv = 1.f / ld;
                sDinv[j] = inv;
            }
            float invj = __shfl(inv, j);
            float cr = ar_[j], ci = ai_[j];
#pragma unroll
            for (int k = 0; k < 8; ++k) if (k < j) {
                float Ljrk = __shfl(Lr_[k], j);
                float Ljik = __shfl(Li_[k], j);
                cr -= Lr_[k]*Ljrk + Li_[k]*Ljik;
                ci -= Li_[k]*Ljrk - Lr_[k]*Ljik;
            }
            if (lane < 8 && lane > j) { Lr_[j] = cr * invj; Li_[j] = ci * invj; }
        }
        if (lane < 8) {
#pragma unroll
            for (int k = 0; k < 8; ++k) if (k <= lane) { sL[lane][k][0] = Lr_[k]; sL[lane][k][1] = Li_[k]; }
        }
        if (lane < 5) {
            float rr[8], ri[8], zr[8], zi[8];
            if (lane == 0) {
#pragma unroll
                for (int i = 0; i < 8; ++i) { rr[i] = yr[b*8+i]; ri[i] = yi[b*8+i]; }
            } else {
#pragma unroll
                for (int i = 0; i < 8; ++i) { rr[i] = hr[(b*8+i)*4 + (lane-1)]; ri[i] = hi[(b*8+i)*4 + (lane-1)]; }
            }
#pragma unroll
            for (int i = 0; i < 8; ++i) {
                float cr = rr[i], ci = ri[i];
#pragma unroll
                for (int k = 0; k < 8; ++k) if (k < i) {
                    cr -= sL[i][k][0]*zr[k] - sL[i][k][1]*zi[k];
                    ci -= sL[i][k][0]*zi[k] + sL[i][k][1]*zr[k];
                }
                float dv = sDinv[i];
                zr[i] = cr * dv; zi[i] = ci * dv;
                if (lane == 0) { lyw[i][0] = zr[i]; lyw[i][1] = zi[i]; }
                else           { lhw[i][lane-1][0] = zr[i]; lhw[i][lane-1][1] = zi[i]; }
            }
        }
    }
    __syncthreads();   // 1

    // ---------------- Gram (15 tiny dot jobs; pair map validated R6) ----------------
    if (t < 15) {
        if (t < 4) {
            float s = 0.f;
#pragma unroll
            for (int m = 0; m < 8; ++m) {
                float ar = lhw[m][t][0], ai = lhw[m][t][1];
                s = fmaf(ar, ar, fmaf(ai, ai, s));
            }
            gdiag[t] = s;
        } else if (t < 10) {
            const int pi = t - 4;
            const int pa = (pi < 3) ? 0 : ((pi < 5) ? 1 : 2);
            const int pb = (pi < 3) ? pi + 1 : ((pi < 5) ? pi - 1 : 3);
            float srr = 0.f, sii = 0.f;
#pragma unroll
            for (int m = 0; m < 8; ++m) {
                float ar = lhw[m][pa][0], ai = lhw[m][pa][1];
                float br = lhw[m][pb][0], bi = lhw[m][pb][1];
                srr = fmaf(ar, br, fmaf(ai, bi, srr));
                sii = fmaf(ar, bi, fmaf(-ai, br, sii));
            }
            gr2[pi] = srr; gi2[pi] = sii;
        } else if (t < 14) {
            const int a = t - 10;
            float swr = 0.f, swi = 0.f;
#pragma unroll
            for (int m = 0; m < 8; ++m) {
                float ar = lhw[m][a][0], ai = lhw[m][a][1];
                swr = fmaf(ar, lyw[m][0], fmaf(ai, lyw[m][1], swr));
                swi = fmaf(ar, lyw[m][1], fmaf(-ai, lyw[m][0], swi));
            }
            wr_[a] = swr; wi_[a] = swi;
        } else {
            float s = 0.f;
#pragma unroll
            for (int m = 0; m < 8; ++m)
                s = fmaf(lyw[m][0], lyw[m][0], fmaf(lyw[m][1], lyw[m][1], s));
            u2s = LOG2E * s;
        }
    }
    __syncthreads();   // 2

    // ---------------- tables (validated R6) ----------------
    if (t < 64) {
        const int a = t >> 4, v = t & 15;
        float pn2 = ptr_[v]*ptr_[v] + pti_[v]*pti_[v];
        G2[a][v] = LOG2E * (pn2 * gdiag[a] - 2.f*(ptr_[v]*wr_[a] + pti_[v]*wi_[a]));
    }
#pragma unroll
    for (int e = t; e < 1536; e += 256) {
        const int tb = e >> 8, va = (e >> 4) & 15, vb = e & 15;
        float dotr = ptr_[va]*ptr_[vb] + pti_[va]*pti_[vb];
        float doti = ptr_[va]*pti_[vb] - pti_[va]*ptr_[vb];
        P2[tb][va][vb] = 2.f * LOG2E * (dotr*gr2[tb] - doti*gi2[tb]);
    }
    __syncthreads();   // 3

    // ---------------- iteration-invariant per-thread pieces (R4 pattern) ----------------
    const float Kpart = u2s + G2[2][i2] + G2[3][i3] + P2[5][i2][i3];
    float Rp[16];
#pragma unroll
    for (int s = 0; s < 16; ++s)
        Rp[s] = G2[1][s] + P2[3][s][i2] + P2[4][s][i3];

    // ---------------- 2 chunk-iterations ----------------
    for (int it = 0; it < 2; ++it) {
        const int chunk = g * 2 + it;
        const float Kit = Kpart + G2[0][chunk] + P2[1][chunk][i2] + P2[2][chunk][i3];
        float xl[16];
        float vmA = -3.4e38f;
#pragma unroll
        for (int s = 0; s < 16; ++s) {
            float x = -(Kit + Rp[s] + P2[0][chunk][s]);
            xl[s] = x;
            vmA = fmaxf(vmA, x);
            xbuf[s][t] = x;
        }
        pmax[t] = vmA;
        __syncthreads();   // 4

        // 2a: row-cluster maxes (j1) + M2/M3 (rotated reads, validated R3/R4/R9)
        {
            float m = -3.4e38f;
#pragma unroll
            for (int j = 0; j < 16; ++j) m = fmaxf(m, xbuf[i3][i2*16 + ((j + i3) & 15)]);
            cm[i3][i2] = m;
        }
        if (t < 16) {
            float m = -3.4e38f;
#pragma unroll
            for (int j = 0; j < 16; ++j) m = fmaxf(m, pmax[t*16 + ((j + t) & 15)]);
            m2b[t] = m;
        } else if (t < 32) {
            const int d = t - 16;
            float m = -3.4e38f;
#pragma unroll
            for (int j = 0; j < 16; ++j) m = fmaxf(m, pmax[d + 16*((j + d) & 15)]);
            m3b[d] = m;
        }
        __syncthreads();   // 5

        // 2b: M1; shared-exp j2/j3 partials
        if (t < 16) {
            float m = -3.4e38f;
#pragma unroll
            for (int j = 0; j < 16; ++j) m = fmaxf(m, cm[t][j]);
            m1b[t] = m;
        }
        const float M2 = m2b[i2], M3 = m3b[i3];
        const float Mlo = fminf(M2, M3);
        float acc = 0.f;
#pragma unroll
        for (int s = 0; s < 16; ++s) acc += EXP2(xl[s] - Mlo);
        part2[t] = acc * EXP2(Mlo - M2);
        part3[t] = acc * EXP2(Mlo - M3);
        __syncthreads();   // 6

        // 2c: j1 exp-sums; j2/j3 group sums -> pairs (agent-scope stores)
        {
            const float M1 = m1b[i3];
            float ssum = 0.f;
#pragma unroll
            for (int j = 0; j < 16; ++j)
                ssum += EXP2(xbuf[i3][i2*16 + ((j + i3) & 15)] - M1);
            cm[i3][i2] = ssum;
        }
        if (t < 16) {
            float S2 = 0.f;
#pragma unroll
            for (int j = 0; j < 16; ++j) S2 += part2[t*16 + ((j + t) & 15)];
            s2b[t] = S2;
            float* w = pairs + ((b*48 + 16 + t)*16 + chunk)*2;
            __hip_atomic_store(&w[0], m2b[t], __ATOMIC_RELAXED, __HIP_MEMORY_SCOPE_AGENT);
            __hip_atomic_store(&w[1], S2,     __ATOMIC_RELAXED, __HIP_MEMORY_SCOPE_AGENT);
        } else if (t < 32) {
            const int d = t - 16;
            float S3 = 0.f;
#pragma unroll
            for (int j = 0; j < 16; ++j) S3 += part3[d + 16*((j + d) & 15)];
            float* w = pairs + ((b*48 + 32 + d)*16 + chunk)*2;
            __hip_atomic_store(&w[0], m3b[d], __ATOMIC_RELAXED, __HIP_MEMORY_SCOPE_AGENT);
            __hip_atomic_store(&w[1], S3,     __ATOMIC_RELAXED, __HIP_MEMORY_SCOPE_AGENT);
        }
        __syncthreads();   // 7

        // j1 pairs + j0 finalize
        if (t < 16) {
            float S1 = 0.f;
#pragma unroll
            for (int j = 0; j < 16; ++j) S1 += cm[t][j];
            float* w = pairs + ((b*48 + t)*16 + chunk)*2;
            __hip_atomic_store(&w[0], m1b[t], __ATOMIC_RELAXED, __HIP_MEMORY_SCOPE_AGENT);
            __hip_atomic_store(&w[1], S1,     __ATOMIC_RELAXED, __HIP_MEMORY_SCOPE_AGENT);
        }
        if (t == 16) {
            float M0 = m2b[0];
#pragma unroll
            for (int i = 1; i < 16; ++i) M0 = fmaxf(M0, m2b[i]);
            float S0 = 0.f;
#pragma unroll
            for (int i = 0; i < 16; ++i) S0 += s2b[i] * EXP2(m2b[i] - M0);
            out[b*64 + chunk] = LN2 * (LOG2(S0) + M0);
        }
        __syncthreads();   // 8: drains vmcnt(0); also guards xbuf reuse next it
    }

    // ---------------- flag publish + merger (g==7, wave0 only) ----------------
    if (t == 0)
        __hip_atomic_store(&flags[b*8 + g], MAGIC, __ATOMIC_RELAXED,
                           __HIP_MEMORY_SCOPE_AGENT);
    if (g == 7 && t < 64) {
        for (;;) {
            int ok = (t >= 8) ||
                (__hip_atomic_load(&flags[b*8 + t], __ATOMIC_RELAXED,
                                   __HIP_MEMORY_SCOPE_AGENT) == MAGIC);
            if (__all(ok)) break;
            __builtin_amdgcn_s_sleep(1);
        }
        if (t < 48) {
            const float* p = pairs + ((b*48 + t)*16)*2;
            float Mv[16], Sv[16];
            float M = -3.4e38f;
#pragma unroll
            for (int i = 0; i < 16; ++i) {
                Mv[i] = __hip_atomic_load(&p[2*i],   __ATOMIC_RELAXED, __HIP_MEMORY_SCOPE_AGENT);
                Sv[i] = __hip_atomic_load(&p[2*i+1], __ATOMIC_RELAXED, __HIP_MEMORY_SCOPE_AGENT);
                M = fmaxf(M, Mv[i]);
            }
            float S = 0.f;
#pragma unroll
            for (int i = 0; i < 16; ++i) S += Sv[i] * EXP2(Mv[i] - M);
            out[b*64 + 16 + t] = LN2 * (LOG2(S) + M);
        }
    }
}

extern "C" void kernel_launch(void* const* d_in, const int* in_sizes, int n_in,
                              void* d_out, int out_size, void* d_ws, size_t ws_size,
                              hipStream_t stream) {
    const float* yr = (const float*)d_in[0];
    const float* yi = (const float*)d_in[1];
    const float* hr = (const float*)d_in[2];
    const float* hi = (const float*)d_in[3];
    const float* sr = (const float*)d_in[4];
    const float* si = (const float*)d_in[5];
    const float* vr = (const float*)d_in[6];
    const float* vi = (const float*)d_in[7];
    float* pairs = (float*)d_ws;                       // [64][48][16][2] floats
    unsigned* flags = (unsigned*)d_ws + 64*48*16*2;    // 512 uints after pairs
    float* out = (float*)d_out;
    // DIAGNOSTIC: two identical dispatches. Delta vs R10 wall = true kernel dur.
    hipLaunchKernelGGL(k_fused, dim3(512), dim3(256), 0, stream,
                       yr, yi, hr, hi, sr, si, vr, vi, flags, pairs, out);
    hipLaunchKernelGGL(k_fused, dim3(512), dim3(256), 0, stream,
                       yr, yi, hr, hi, sr, si, vr, vi, flags, pairs, out);
}

// Round 13
// 23.992 us; speedup vs baseline: 1.4543x; 1.4543x over previous
//
#include <hip/hip_runtime.h>
#include <math.h>

#define LOG2E 1.4426950408889634f
#define LN2   0.6931471805599453f

#if __has_builtin(__builtin_amdgcn_exp2f)
#define EXP2(x) __builtin_amdgcn_exp2f(x)
#else
#define EXP2(x) exp2f(x)
#endif
#if __has_builtin(__builtin_amdgcn_logf)
#define LOG2(x) __builtin_amdgcn_logf(x)
#else
#define LOG2(x) log2f(x)
#endif

// B=64, M=8, K=4, P=16, V=65536. ONE dispatch, 64 blocks (1 batch each) x 256 thr.
// Thread t owns (d2,d3) = (t>>4, t&15) and scans all 256 (d0,d1) candidates in
// registers (two-pass: maxes then exp2-sums; fully unrolled -> register arrays).
// j0/j1 merges via LDS 2-stage LSE; j2/j3 are whole-thread groups (1 pair each).
// No workspace, no flags, no agent atomics, no cross-block communication.
// x via R6-validated Gram factorization: x = A[d0] + Bv[d1] - P01[d0][d1].

__global__ __launch_bounds__(256, 1) void k_all(
    const float* __restrict__ yr, const float* __restrict__ yi,
    const float* __restrict__ hr, const float* __restrict__ hi,
    const float* __restrict__ sr, const float* __restrict__ si,
    const float* __restrict__ vr, const float* __restrict__ vi,
    float* __restrict__ out)
{
    __shared__ float sL[8][8][2];
    __shared__ float sDinv[8];
    __shared__ float lyw[8][2];
    __shared__ float lhw[8][4][2];     // whitened h [m][k]
    __shared__ float ptr_[16], pti_[16];
    __shared__ float gdiag[4];
    __shared__ float gr2[6], gi2[6];   // pairs (01,02,03,12,13,23)
    __shared__ float wr_[4], wi_[4];
    __shared__ float u2s;              // LOG2E * |yw|^2
    __shared__ float G2[4][16];        // LOG2E * G_a[v]
    __shared__ float P2[6][16][16];    // 2*LOG2E * P_ab[va][vb]
    __shared__ float Lm[16][257], Ls[16][257];  // [group][src thread] pair bufs
    __shared__ float Qm[16][17], Qs[16][17];    // stage-1 outputs
    __shared__ float Tm[257], Ts[257];          // per-thread totals (j2/j3)

    const int t = threadIdx.x;
    const int b = blockIdx.x;
    const int i2 = t >> 4, i3 = t & 15;

    if (t < 16) { ptr_[t] = vr[(t << 12) * 4]; pti_[t] = vi[(t << 12) * 4]; }

    // ---------------- wave 0: whiten (validated R2..R10) ----------------
    if (t < 64) {
        const int lane = t;
        float ar_[8] = {}, ai_[8] = {}, Lr_[8] = {}, Li_[8] = {};
        if (lane < 8) {
#pragma unroll
            for (int k = 0; k < 8; ++k) {
                ar_[k] = sr[b * 64 + lane * 8 + k];
                ai_[k] = si[b * 64 + lane * 8 + k];
            }
        }
        float inv = 0.f;
#pragma unroll
        for (int j = 0; j < 8; ++j) {
            if (lane == j) {
                float d = ar_[j];
#pragma unroll
                for (int k = 0; k < 8; ++k) if (k < j) d -= Lr_[k]*Lr_[k] + Li_[k]*Li_[k];
                float ld = sqrtf(d);
                Lr_[j] = ld; Li_[j] = 0.f;
                inv = 1.f / ld;
                sDinv[j] = inv;
            }
            float invj = __shfl(inv, j);
            float cr = ar_[j], ci = ai_[j];
#pragma unroll
            for (int k = 0; k < 8; ++k) if (k < j) {
                float Ljrk = __shfl(Lr_[k], j);
                float Ljik = __shfl(Li_[k], j);
                cr -= Lr_[k]*Ljrk + Li_[k]*Ljik;
                ci -= Li_[k]*Ljrk - Lr_[k]*Ljik;
            }
            if (lane < 8 && lane > j) { Lr_[j] = cr * invj; Li_[j] = ci * invj; }
        }
        if (lane < 8) {
#pragma unroll
            for (int k = 0; k < 8; ++k) if (k <= lane) { sL[lane][k][0] = Lr_[k]; sL[lane][k][1] = Li_[k]; }
        }
        if (lane < 5) {
            float rr[8], ri[8], zr[8], zi[8];
            if (lane == 0) {
#pragma unroll
                for (int i = 0; i < 8; ++i) { rr[i] = yr[b*8+i]; ri[i] = yi[b*8+i]; }
            } else {
#pragma unroll
                for (int i = 0; i < 8; ++i) { rr[i] = hr[(b*8+i)*4 + (lane-1)]; ri[i] = hi[(b*8+i)*4 + (lane-1)]; }
            }
#pragma unroll
            for (int i = 0; i < 8; ++i) {
                float cr = rr[i], ci = ri[i];
#pragma unroll
                for (int k = 0; k < 8; ++k) if (k < i) {
                    cr -= sL[i][k][0]*zr[k] - sL[i][k][1]*zi[k];
                    ci -= sL[i][k][0]*zi[k] + sL[i][k][1]*zr[k];
                }
                float dv = sDinv[i];
                zr[i] = cr * dv; zi[i] = ci * dv;
                if (lane == 0) { lyw[i][0] = zr[i]; lyw[i][1] = zi[i]; }
                else           { lhw[i][lane-1][0] = zr[i]; lhw[i][lane-1][1] = zi[i]; }
            }
        }
    }
    __syncthreads();   // 1

    // ---------------- Gram (validated R6) ----------------
    if (t < 15) {
        if (t < 4) {
            float s = 0.f;
#pragma unroll
            for (int m = 0; m < 8; ++m) {
                float ar = lhw[m][t][0], ai = lhw[m][t][1];
                s = fmaf(ar, ar, fmaf(ai, ai, s));
            }
            gdiag[t] = s;
        } else if (t < 10) {
            const int pi = t - 4;
            const int pa = (pi < 3) ? 0 : ((pi < 5) ? 1 : 2);
            const int pb = (pi < 3) ? pi + 1 : ((pi < 5) ? pi - 1 : 3);
            float srr = 0.f, sii = 0.f;
#pragma unroll
            for (int m = 0; m < 8; ++m) {
                float ar = lhw[m][pa][0], ai = lhw[m][pa][1];
                float br = lhw[m][pb][0], bi = lhw[m][pb][1];
                srr = fmaf(ar, br, fmaf(ai, bi, srr));
                sii = fmaf(ar, bi, fmaf(-ai, br, sii));
            }
            gr2[pi] = srr; gi2[pi] = sii;
        } else if (t < 14) {
            const int a = t - 10;
            float swr = 0.f, swi = 0.f;
#pragma unroll
            for (int m = 0; m < 8; ++m) {
                float ar = lhw[m][a][0], ai = lhw[m][a][1];
                swr = fmaf(ar, lyw[m][0], fmaf(ai, lyw[m][1], swr));
                swi = fmaf(ar, lyw[m][1], fmaf(-ai, lyw[m][0], swi));
            }
            wr_[a] = swr; wi_[a] = swi;
        } else {
            float s = 0.f;
#pragma unroll
            for (int m = 0; m < 8; ++m)
                s = fmaf(lyw[m][0], lyw[m][0], fmaf(lyw[m][1], lyw[m][1], s));
            u2s = LOG2E * s;
        }
    }
    __syncthreads();   // 2

    // ---------------- tables (validated R6) ----------------
    if (t < 64) {
        const int a = t >> 4, v = t & 15;
        float pn2 = ptr_[v]*ptr_[v] + pti_[v]*pti_[v];
        G2[a][v] = LOG2E * (pn2 * gdiag[a] - 2.f*(ptr_[v]*wr_[a] + pti_[v]*wi_[a]));
    }
#pragma unroll
    for (int e = t; e < 1536; e += 256) {
        const int tb = e >> 8, va = (e >> 4) & 15, vb = e & 15;
        float dotr = ptr_[va]*ptr_[vb] + pti_[va]*pti_[vb];
        float doti = ptr_[va]*pti_[vb] - pti_[va]*ptr_[vb];
        P2[tb][va][vb] = 2.f * LOG2E * (dotr*gr2[tb] - doti*gi2[tb]);
    }
    __syncthreads();   // 3

    // ---------------- per-thread A/B vectors ----------------
    const float Cst = u2s + G2[2][i2] + G2[3][i3] + P2[5][i2][i3];
    float A[16], Bv[16];
#pragma unroll
    for (int v = 0; v < 16; ++v) {
        A[v]  = -(Cst + G2[0][v] + P2[1][v][i2] + P2[2][v][i3]);
        Bv[v] = -(G2[1][v] + P2[3][v][i2] + P2[4][v][i3]);
    }

    // ---------------- pass 1: per-group maxes ----------------
    float j0m[16], j1m[16];
#pragma unroll
    for (int v = 0; v < 16; ++v) { j0m[v] = -3.4e38f; j1m[v] = -3.4e38f; }
#pragma unroll
    for (int d0 = 0; d0 < 16; ++d0) {
#pragma unroll
        for (int d1 = 0; d1 < 16; ++d1) {
            float x = A[d0] + Bv[d1] - P2[0][d0][d1];
            j0m[d0] = fmaxf(j0m[d0], x);
            j1m[d1] = fmaxf(j1m[d1], x);
        }
    }
    asm volatile("" ::: "memory");   // keep pass2 from caching pass1's x values

    // ---------------- pass 2: per-group exp2-sums ----------------
    float j0s[16], j1s[16];
#pragma unroll
    for (int v = 0; v < 16; ++v) { j0s[v] = 0.f; j1s[v] = 0.f; }
#pragma unroll
    for (int d0 = 0; d0 < 16; ++d0) {
        float s0 = 0.f;
#pragma unroll
        for (int d1 = 0; d1 < 16; ++d1) {
            float x = A[d0] + Bv[d1] - P2[0][d0][d1];
            s0     += EXP2(x - j0m[d0]);
            j1s[d1] += EXP2(x - j1m[d1]);
        }
        j0s[d0] = s0;
    }

    // ---------------- per-thread total (j2/j3 partial pair) ----------------
    float Mt = j0m[0];
#pragma unroll
    for (int v = 1; v < 16; ++v) Mt = fmaxf(Mt, j0m[v]);
    float St = 0.f;
#pragma unroll
    for (int v = 0; v < 16; ++v) St += j0s[v] * EXP2(j0m[v] - Mt);

    // ---------------- j0 merge (2-stage LSE over 256 threads) ----------------
#pragma unroll
    for (int g = 0; g < 16; ++g) { Lm[g][t] = j0m[g]; Ls[g][t] = j0s[g]; }
    __syncthreads();   // 4
    {
        const int g = i2, h = i3;
        float mv[16], sv[16], M = -3.4e38f;
#pragma unroll
        for (int i = 0; i < 16; ++i) {
            int r = h*16 + ((i + h) & 15);
            mv[i] = Lm[g][r]; sv[i] = Ls[g][r];
            M = fmaxf(M, mv[i]);
        }
        float S = 0.f;
#pragma unroll
        for (int i = 0; i < 16; ++i) S += sv[i] * EXP2(mv[i] - M);
        Qm[g][h] = M; Qs[g][h] = S;
    }
    __syncthreads();   // 5
    if (t < 16) {      // stage 2 -> j0 logits
        float mv[16], sv[16], M = -3.4e38f;
#pragma unroll
        for (int h = 0; h < 16; ++h) {
            mv[h] = Qm[t][h]; sv[h] = Qs[t][h];
            M = fmaxf(M, mv[h]);
        }
        float S = 0.f;
#pragma unroll
        for (int h = 0; h < 16; ++h) S += sv[h] * EXP2(mv[h] - M);
        out[b*64 + t] = LN2 * (LOG2(S) + M);
    }
    // write j1 pairs (Lm free: stage1 readers done at barrier 5)
#pragma unroll
    for (int g = 0; g < 16; ++g) { Lm[g][t] = j1m[g]; Ls[g][t] = j1s[g]; }
    __syncthreads();   // 6
    {
        const int g = i2, h = i3;
        float mv[16], sv[16], M = -3.4e38f;
#pragma unroll
        for (int i = 0; i < 16; ++i) {
            int r = h*16 + ((i + h) & 15);
            mv[i] = Lm[g][r]; sv[i] = Ls[g][r];
            M = fmaxf(M, mv[i]);
        }
        float S = 0.f;
#pragma unroll
        for (int i = 0; i < 16; ++i) S += sv[i] * EXP2(mv[i] - M);
        Qm[g][h] = M; Qs[g][h] = S;
    }
    __syncthreads();   // 7
    if (t < 16) {      // stage 2 -> j1 logits
        float mv[16], sv[16], M = -3.4e38f;
#pragma unroll
        for (int h = 0; h < 16; ++h) {
            mv[h] = Qm[t][h]; sv[h] = Qs[t][h];
            M = fmaxf(M, mv[h]);
        }
        float S = 0.f;
#pragma unroll
        for (int h = 0; h < 16; ++h) S += sv[h] * EXP2(mv[h] - M);
        out[b*64 + 16 + t] = LN2 * (LOG2(S) + M);
    }
    // publish per-thread totals for j2/j3
    Tm[t] = Mt; Ts[t] = St;
    __syncthreads();   // 8
    if (t < 16) {      // j2 group t: threads t*16 .. t*16+15 (contiguous)
        float mv[16], sv[16], M = -3.4e38f;
#pragma unroll
        for (int i = 0; i < 16; ++i) {
            int r = t*16 + ((i + t) & 15);
            mv[i] = Tm[r]; sv[i] = Ts[r];
            M = fmaxf(M, mv[i]);
        }
        float S = 0.f;
#pragma unroll
        for (int i = 0; i < 16; ++i) S += sv[i] * EXP2(mv[i] - M);
        out[b*64 + 32 + t] = LN2 * (LOG2(S) + M);
    } else if (t < 32) { // j3 group p: threads p, p+16, ... (stride 16)
        const int p = t - 16;
        float mv[16], sv[16], M = -3.4e38f;
#pragma unroll
        for (int i = 0; i < 16; ++i) {
            int r = ((i + p) & 15)*16 + p;
            mv[i] = Tm[r]; sv[i] = Ts[r];
            M = fmaxf(M, mv[i]);
        }
        float S = 0.f;
#pragma unroll
        for (int i = 0; i < 16; ++i) S += sv[i] * EXP2(mv[i] - M);
        out[b*64 + 48 + p] = LN2 * (LOG2(S) + M);
    }
}

extern "C" void kernel_launch(void* const* d_in, const int* in_sizes, int n_in,
                              void* d_out, int out_size, void* d_ws, size_t ws_size,
                              hipStream_t stream) {
    const float* yr = (const float*)d_in[0];
    const float* yi = (const float*)d_in[1];
    const float* hr = (const float*)d_in[2];
    const float* hi = (const float*)d_in[3];
    const float* sr = (const float*)d_in[4];
    const float* si = (const float*)d_in[5];
    const float* vr = (const float*)d_in[6];
    const float* vi = (const float*)d_in[7];
    float* out = (float*)d_out;
    hipLaunchKernelGGL(k_all, dim3(64), dim3(256), 0, stream,
                       yr, yi, hr, hi, sr, si, vr, vi, out);
}

// Round 14
// 21.532 us; speedup vs baseline: 1.6204x; 1.1143x over previous
//
#include <hip/hip_runtime.h>
#include <math.h>

#define LOG2E 1.4426950408889634f
#define LN2   0.6931471805599453f

#if __has_builtin(__builtin_amdgcn_exp2f)
#define EXP2(x) __builtin_amdgcn_exp2f(x)
#else
#define EXP2(x) exp2f(x)
#endif
#if __has_builtin(__builtin_amdgcn_logf)
#define LOG2(x) __builtin_amdgcn_logf(x)
#else
#define LOG2(x) log2f(x)
#endif

// B=64, M=8, K=4, P=16, V=65536. ONE dispatch: 4096 blocks (= 64 batches x 64
// groups) x 64 threads (single wave). Each block computes ONE logit:
// LSE over the 4096 candidates whose digit_j == p.
//   digits: v = d0*4096 + d1*256 + d2*16 + d3; block group g6 = j*16+p.
//   free digits (s, a, dB); thread owns dB = t&15, hi2 = t>>4; a = ai*4+hi2.
//   y = CK[a] + CT[s] + PA[s][a]  (log2-domain, from R6-validated Gram tables);
//   x = -y; LSE via group min of y (6-shfl butterfly), exp2 re-pass, sum
//   butterfly, lane 0 writes out[b*64 + g6].
// No workspace, no atomics, no flags, no cross-block traffic, ~5 barriers.
// Whiten head (validated R2..R10) runs redundantly per block -- parallel, free.

__global__ __launch_bounds__(64) void k_grp(
    const float* __restrict__ yr, const float* __restrict__ yi,
    const float* __restrict__ hr, const float* __restrict__ hi,
    const float* __restrict__ sr, const float* __restrict__ si,
    const float* __restrict__ vr, const float* __restrict__ vi,
    float* __restrict__ out)
{
    __shared__ float sL[8][8][2];
    __shared__ float sDinv[8];
    __shared__ float lyw[8][2];
    __shared__ float lhw[8][4][2];     // whitened h [m][k]
    __shared__ float ptr_[16], pti_[16];
    __shared__ float gdiag[4];
    __shared__ float gr2[6], gi2[6];   // pairs (01,02,03,12,13,23)
    __shared__ float wr_[4], wi_[4];
    __shared__ float u2s_s;            // LOG2E * |yw|^2
    __shared__ float G2[4][16];        // LOG2E * G_a[v]
    __shared__ float P2[6][16][16];    // 2*LOG2E * P_ab[va][vb]

    const int t = threadIdx.x;
    const int b = blockIdx.x >> 6, g6 = blockIdx.x & 63;
    const int j = g6 >> 4, p = g6 & 15;
    const int dB = t & 15, hi2 = t >> 4;

    if (t < 16) { ptr_[t] = vr[(t << 12) * 4]; pti_[t] = vi[(t << 12) * 4]; }

    // ---------------- whiten (validated R2..R10; single wave) ----------------
    {
        const int lane = t;
        float ar_[8] = {}, ai_[8] = {}, Lr_[8] = {}, Li_[8] = {};
        if (lane < 8) {
#pragma unroll
            for (int k = 0; k < 8; ++k) {
                ar_[k] = sr[b * 64 + lane * 8 + k];
                ai_[k] = si[b * 64 + lane * 8 + k];
            }
        }
        float inv = 0.f;
#pragma unroll
        for (int jj = 0; jj < 8; ++jj) {
            if (lane == jj) {
                float d = ar_[jj];
#pragma unroll
                for (int k = 0; k < 8; ++k) if (k < jj) d -= Lr_[k]*Lr_[k] + Li_[k]*Li_[k];
                float ld = sqrtf(d);
                Lr_[jj] = ld; Li_[jj] = 0.f;
                inv = 1.f / ld;
                sDinv[jj] = inv;
            }
            float invj = __shfl(inv, jj);
            float cr = ar_[jj], ci = ai_[jj];
#pragma unroll
            for (int k = 0; k < 8; ++k) if (k < jj) {
                float Ljrk = __shfl(Lr_[k], jj);
                float Ljik = __shfl(Li_[k], jj);
                cr -= Lr_[k]*Ljrk + Li_[k]*Ljik;
                ci -= Li_[k]*Ljrk - Lr_[k]*Ljik;
            }
            if (lane < 8 && lane > jj) { Lr_[jj] = cr * invj; Li_[jj] = ci * invj; }
        }
        if (lane < 8) {
#pragma unroll
            for (int k = 0; k < 8; ++k) if (k <= lane) { sL[lane][k][0] = Lr_[k]; sL[lane][k][1] = Li_[k]; }
        }
        if (lane < 5) {
            float rr[8], ri[8], zr[8], zi[8];
            if (lane == 0) {
#pragma unroll
                for (int i = 0; i < 8; ++i) { rr[i] = yr[b*8+i]; ri[i] = yi[b*8+i]; }
            } else {
#pragma unroll
                for (int i = 0; i < 8; ++i) { rr[i] = hr[(b*8+i)*4 + (lane-1)]; ri[i] = hi[(b*8+i)*4 + (lane-1)]; }
            }
#pragma unroll
            for (int i = 0; i < 8; ++i) {
                float cr = rr[i], ci = ri[i];
#pragma unroll
                for (int k = 0; k < 8; ++k) if (k < i) {
                    cr -= sL[i][k][0]*zr[k] - sL[i][k][1]*zi[k];
                    ci -= sL[i][k][0]*zi[k] + sL[i][k][1]*zr[k];
                }
                float dv = sDinv[i];
                zr[i] = cr * dv; zi[i] = ci * dv;
                if (lane == 0) { lyw[i][0] = zr[i]; lyw[i][1] = zi[i]; }
                else           { lhw[i][lane-1][0] = zr[i]; lhw[i][lane-1][1] = zi[i]; }
            }
        }
    }
    __syncthreads();   // 1

    // ---------------- Gram (validated R6) ----------------
    if (t < 15) {
        if (t < 4) {
            float s = 0.f;
#pragma unroll
            for (int m = 0; m < 8; ++m) {
                float ar = lhw[m][t][0], ai = lhw[m][t][1];
                s = fmaf(ar, ar, fmaf(ai, ai, s));
            }
            gdiag[t] = s;
        } else if (t < 10) {
            const int pi = t - 4;
            const int pa = (pi < 3) ? 0 : ((pi < 5) ? 1 : 2);
            const int pb = (pi < 3) ? pi + 1 : ((pi < 5) ? pi - 1 : 3);
            float srr = 0.f, sii = 0.f;
#pragma unroll
            for (int m = 0; m < 8; ++m) {
                float ar = lhw[m][pa][0], ai = lhw[m][pa][1];
                float br = lhw[m][pb][0], bi = lhw[m][pb][1];
                srr = fmaf(ar, br, fmaf(ai, bi, srr));
                sii = fmaf(ar, bi, fmaf(-ai, br, sii));
            }
            gr2[pi] = srr; gi2[pi] = sii;
        } else if (t < 14) {
            const int a = t - 10;
            float swr = 0.f, swi = 0.f;
#pragma unroll
            for (int m = 0; m < 8; ++m) {
                float ar = lhw[m][a][0], ai = lhw[m][a][1];
                swr = fmaf(ar, lyw[m][0], fmaf(ai, lyw[m][1], swr));
                swi = fmaf(ar, lyw[m][1], fmaf(-ai, lyw[m][0], swi));
            }
            wr_[a] = swr; wi_[a] = swi;
        } else {
            float s = 0.f;
#pragma unroll
            for (int m = 0; m < 8; ++m)
                s = fmaf(lyw[m][0], lyw[m][0], fmaf(lyw[m][1], lyw[m][1], s));
            u2s_s = LOG2E * s;
        }
    }
    __syncthreads();   // 2

    // ---------------- tables (validated R6) ----------------
    {
        const int a = t >> 4, v = t & 15;       // t<64 covers all [4][16]
        float pn2 = ptr_[v]*ptr_[v] + pti_[v]*pti_[v];
        G2[a][v] = LOG2E * (pn2 * gdiag[a] - 2.f*(ptr_[v]*wr_[a] + pti_[v]*wi_[a]));
    }
#pragma unroll
    for (int e = t; e < 1536; e += 64) {
        const int tb = e >> 8, va = (e >> 4) & 15, vb = e & 15;
        float dotr = ptr_[va]*ptr_[vb] + pti_[va]*pti_[vb];
        float doti = ptr_[va]*pti_[vb] - pti_[va]*ptr_[vb];
        P2[tb][va][vb] = 2.f * LOG2E * (dotr*gr2[tb] - doti*gi2[tb]);
    }
    __syncthreads();   // 3

    // ---------------- per-thread CK/CT (j-specialized; digit maps verified) ----------------
    const float u2s = u2s_s;
    float CT[16], CKt[4];
    const float* PAb;   // per-candidate pair table: y += PAb[s*16 + a]
    if (j == 0) {            // fixed d0=p; s=d1, a=d2, dB=d3
        PAb = &P2[3][0][0];
#pragma unroll
        for (int s = 0; s < 16; ++s) CT[s] = G2[1][s] + P2[0][p][s] + P2[4][s][dB];
#pragma unroll
        for (int ai = 0; ai < 4; ++ai) {
            int a = ai*4 + hi2;
            CKt[ai] = u2s + G2[0][p] + G2[2][a] + G2[3][dB]
                    + P2[1][p][a] + P2[2][p][dB] + P2[5][a][dB];
        }
    } else if (j == 1) {     // fixed d1=p; s=d0, a=d2, dB=d3
        PAb = &P2[1][0][0];
#pragma unroll
        for (int s = 0; s < 16; ++s) CT[s] = G2[0][s] + P2[0][s][p] + P2[2][s][dB];
#pragma unroll
        for (int ai = 0; ai < 4; ++ai) {
            int a = ai*4 + hi2;
            CKt[ai] = u2s + G2[1][p] + G2[2][a] + G2[3][dB]
                    + P2[3][p][a] + P2[4][p][dB] + P2[5][a][dB];
        }
    } else if (j == 2) {     // fixed d2=p; s=d0, a=d1, dB=d3
        PAb = &P2[0][0][0];
#pragma unroll
        for (int s = 0; s < 16; ++s) CT[s] = G2[0][s] + P2[1][s][p] + P2[2][s][dB];
#pragma unroll
        for (int ai = 0; ai < 4; ++ai) {
            int a = ai*4 + hi2;
            CKt[ai] = u2s + G2[2][p] + G2[1][a] + G2[3][dB]
                    + P2[3][a][p] + P2[5][p][dB] + P2[4][a][dB];
        }
    } else {                 // j==3: fixed d3=p; s=d0, a=d1, dB=d2
        PAb = &P2[0][0][0];
#pragma unroll
        for (int s = 0; s < 16; ++s) CT[s] = G2[0][s] + P2[2][s][p] + P2[1][s][dB];
#pragma unroll
        for (int ai = 0; ai < 4; ++ai) {
            int a = ai*4 + hi2;
            CKt[ai] = u2s + G2[3][p] + G2[1][a] + G2[2][dB]
                    + P2[4][a][p] + P2[5][dB][p] + P2[3][a][dB];
        }
    }

    // ---------------- pass 1: group min of y (= -x) ----------------
    float ymin = 3.4e38f;
#pragma unroll
    for (int ai = 0; ai < 4; ++ai) {
        const int a = ai*4 + hi2;
        const float ck = CKt[ai];
#pragma unroll
        for (int s = 0; s < 16; ++s) {
            float y = ck + CT[s] + PAb[s*16 + a];
            ymin = fminf(ymin, y);
        }
    }
    ymin = fminf(ymin, __shfl_xor(ymin, 1));
    ymin = fminf(ymin, __shfl_xor(ymin, 2));
    ymin = fminf(ymin, __shfl_xor(ymin, 4));
    ymin = fminf(ymin, __shfl_xor(ymin, 8));
    ymin = fminf(ymin, __shfl_xor(ymin, 16));
    ymin = fminf(ymin, __shfl_xor(ymin, 32));
    asm volatile("" ::: "memory");   // force pass2 to re-read LDS (no 64-reg CSE)

    // ---------------- pass 2: sum exp2(ymin - y) ----------------
    float Ssum = 0.f;
#pragma unroll
    for (int ai = 0; ai < 4; ++ai) {
        const int a = ai*4 + hi2;
        const float ck = CKt[ai];
#pragma unroll
        for (int s = 0; s < 16; ++s) {
            float y = ck + CT[s] + PAb[s*16 + a];
            Ssum += EXP2(ymin - y);
        }
    }
    Ssum += __shfl_xor(Ssum, 1);
    Ssum += __shfl_xor(Ssum, 2);
    Ssum += __shfl_xor(Ssum, 4);
    Ssum += __shfl_xor(Ssum, 8);
    Ssum += __shfl_xor(Ssum, 16);
    Ssum += __shfl_xor(Ssum, 32);

    if (t == 0)
        out[b*64 + g6] = LN2 * (LOG2(Ssum) - ymin);   // x_max = -ymin
}

extern "C" void kernel_launch(void* const* d_in, const int* in_sizes, int n_in,
                              void* d_out, int out_size, void* d_ws, size_t ws_size,
                              hipStream_t stream) {
    const float* yr = (const float*)d_in[0];
    const float* yi = (const float*)d_in[1];
    const float* hr = (const float*)d_in[2];
    const float* hi = (const float*)d_in[3];
    const float* sr = (const float*)d_in[4];
    const float* si = (const float*)d_in[5];
    const float* vr = (const float*)d_in[6];
    const float* vi = (const float*)d_in[7];
    float* out = (float*)d_out;
    hipLaunchKernelGGL(k_grp, dim3(4096), dim3(64), 0, stream,
                       yr, yi, hr, hi, sr, si, vr, vi, out);
}

// Round 15
// 19.903 us; speedup vs baseline: 1.7530x; 1.0818x over previous
//
#include <hip/hip_runtime.h>
#include <math.h>

#define LOG2E 1.4426950408889634f
#define LN2   0.6931471805599453f
#define MAGIC 0x5EED1234u

#if __has_builtin(__builtin_amdgcn_exp2f)
#define EXP2(x) __builtin_amdgcn_exp2f(x)
#else
#define EXP2(x) exp2f(x)
#endif
#if __has_builtin(__builtin_amdgcn_logf)
#define LOG2(x) __builtin_amdgcn_logf(x)
#else
#define LOG2(x) log2f(x)
#endif

// FINAL FORM (= R10, the empirical minimum across 14 structural variants).
// B=64, M=8, K=4, P=16, V=65536. ONE kernel node, no memset.
// 512 blocks (64 batches x 8), 256 threads, 2 chunks per block.
// Whiten (1-wave cooperative Cholesky) -> 4x4 whitened Gram -> G2/P2 log2-domain
// factorization tables -> x = -(K + R[s] + P01[d0][s]) -> grouped LSE via
// LDS-array reductions (rotated conflict-free reads) -> 48 (max,sum) pairs via
// agent-scope stores -> MAGIC flag handshake -> g==7 block merges j1..j3.
// Floor analysis (R11 2x-probe + R3..R13 sweep): wall = ~15.2us dispatch floor
// + ~4.5us graph overhead, insensitive to body work (R9 vs R10: 2x phases, +0us).

__global__ __launch_bounds__(256) void k_fused(
    const float* __restrict__ yr, const float* __restrict__ yi,
    const float* __restrict__ hr, const float* __restrict__ hi,
    const float* __restrict__ sr, const float* __restrict__ si,
    const float* __restrict__ vr, const float* __restrict__ vi,
    unsigned* __restrict__ flags, float* __restrict__ pairs,
    float* __restrict__ out)
{
    __shared__ float sL[8][8][2];
    __shared__ float sDinv[8];
    __shared__ float lyw[8][2];
    __shared__ float lhw[8][4][2];     // whitened h [m][k]
    __shared__ float ptr_[16], pti_[16];
    __shared__ float gdiag[4];         // g_aa (real)
    __shared__ float gr2[6], gi2[6];   // g_ab for pairs (01,02,03,12,13,23)
    __shared__ float wr_[4], wi_[4];   // w_a = sum_m conj(hw[m,a]) yw[m]
    __shared__ float u2s;              // LOG2E * |yw|^2
    __shared__ float G2[4][16];        // LOG2E * G_a[v]
    __shared__ float P2[6][16][16];    // 2*LOG2E * P_ab[va][vb]
    __shared__ float xbuf[16][256];    // [d1=s][c]
    __shared__ float pmax[256];
    __shared__ float cm[16][17];       // [s][cluster] maxes, reused for j1 sums
    __shared__ float m1b[16], m2b[16], m3b[16], s2b[16];
    __shared__ float part2[256], part3[256];

    const int t = threadIdx.x;
    const int b = blockIdx.x >> 3, g = blockIdx.x & 7;
    const int i2 = t >> 4, i3 = t & 15;

    if (t < 16) { ptr_[t] = vr[(t << 12) * 4]; pti_[t] = vi[(t << 12) * 4]; }

    // ---------------- wave 0: whiten ----------------
    if (t < 64) {
        const int lane = t;
        float ar_[8] = {}, ai_[8] = {}, Lr_[8] = {}, Li_[8] = {};
        if (lane < 8) {
#pragma unroll
            for (int k = 0; k < 8; ++k) {
                ar_[k] = sr[b * 64 + lane * 8 + k];
                ai_[k] = si[b * 64 + lane * 8 + k];
            }
        }
        float inv = 0.f;
#pragma unroll
        for (int j = 0; j < 8; ++j) {
            if (lane == j) {
                float d = ar_[j];
#pragma unroll
                for (int k = 0; k < 8; ++k) if (k < j) d -= Lr_[k]*Lr_[k] + Li_[k]*Li_[k];
                float ld = sqrtf(d);
                Lr_[j] = ld; Li_[j] = 0.f;
                inv = 1.f / ld;
                sDinv[j] = inv;
            }
            float invj = __shfl(inv, j);
            float cr = ar_[j], ci = ai_[j];
#pragma unroll
            for (int k = 0; k < 8; ++k) if (k < j) {
                float Ljrk = __shfl(Lr_[k], j);
                float Ljik = __shfl(Li_[k], j);
                cr -= Lr_[k]*Ljrk + Li_[k]*Ljik;
                ci -= Li_[k]*Ljrk - Lr_[k]*Ljik;
            }
            if (lane < 8 && lane > j) { Lr_[j] = cr * invj; Li_[j] = ci * invj; }
        }
        if (lane < 8) {
#pragma unroll
            for (int k = 0; k < 8; ++k) if (k <= lane) { sL[lane][k][0] = Lr_[k]; sL[lane][k][1] = Li_[k]; }
        }
        if (lane < 5) {
            float rr[8], ri[8], zr[8], zi[8];
            if (lane == 0) {
#pragma unroll
                for (int i = 0; i < 8; ++i) { rr[i] = yr[b*8+i]; ri[i] = yi[b*8+i]; }
            } else {
#pragma unroll
                for (int i = 0; i < 8; ++i) { rr[i] = hr[(b*8+i)*4 + (lane-1)]; ri[i] = hi[(b*8+i)*4 + (lane-1)]; }
            }
#pragma unroll
            for (int i = 0; i < 8; ++i) {
                float cr = rr[i], ci = ri[i];
#pragma unroll
                for (int k = 0; k < 8; ++k) if (k < i) {
                    cr -= sL[i][k][0]*zr[k] - sL[i][k][1]*zi[k];
                    ci -= sL[i][k][0]*zi[k] + sL[i][k][1]*zr[k];
                }
                float dv = sDinv[i];
                zr[i] = cr * dv; zi[i] = ci * dv;
                if (lane == 0) { lyw[i][0] = zr[i]; lyw[i][1] = zi[i]; }
                else           { lhw[i][lane-1][0] = zr[i]; lhw[i][lane-1][1] = zi[i]; }
            }
        }
    }
    __syncthreads();   // 1

    // ---------------- Gram ----------------
    if (t < 15) {
        if (t < 4) {
            float s = 0.f;
#pragma unroll
            for (int m = 0; m < 8; ++m) {
                float ar = lhw[m][t][0], ai = lhw[m][t][1];
                s = fmaf(ar, ar, fmaf(ai, ai, s));
            }
            gdiag[t] = s;
        } else if (t < 10) {
            const int pi = t - 4;
            const int pa = (pi < 3) ? 0 : ((pi < 5) ? 1 : 2);
            const int pb = (pi < 3) ? pi + 1 : ((pi < 5) ? pi - 1 : 3);
            float srr = 0.f, sii = 0.f;
#pragma unroll
            for (int m = 0; m < 8; ++m) {
                float ar = lhw[m][pa][0], ai = lhw[m][pa][1];
                float br = lhw[m][pb][0], bi = lhw[m][pb][1];
                srr = fmaf(ar, br, fmaf(ai, bi, srr));
                sii = fmaf(ar, bi, fmaf(-ai, br, sii));
            }
            gr2[pi] = srr; gi2[pi] = sii;
        } else if (t < 14) {
            const int a = t - 10;
            float swr = 0.f, swi = 0.f;
#pragma unroll
            for (int m = 0; m < 8; ++m) {
                float ar = lhw[m][a][0], ai = lhw[m][a][1];
                swr = fmaf(ar, lyw[m][0], fmaf(ai, lyw[m][1], swr));
                swi = fmaf(ar, lyw[m][1], fmaf(-ai, lyw[m][0], swi));
            }
            wr_[a] = swr; wi_[a] = swi;
        } else {
            float s = 0.f;
#pragma unroll
            for (int m = 0; m < 8; ++m)
                s = fmaf(lyw[m][0], lyw[m][0], fmaf(lyw[m][1], lyw[m][1], s));
            u2s = LOG2E * s;
        }
    }
    __syncthreads();   // 2

    // ---------------- tables ----------------
    if (t < 64) {
        const int a = t >> 4, v = t & 15;
        float pn2 = ptr_[v]*ptr_[v] + pti_[v]*pti_[v];
        G2[a][v] = LOG2E * (pn2 * gdiag[a] - 2.f*(ptr_[v]*wr_[a] + pti_[v]*wi_[a]));
    }
#pragma unroll
    for (int e = t; e < 1536; e += 256) {
        const int tb = e >> 8, va = (e >> 4) & 15, vb = e & 15;
        float dotr = ptr_[va]*ptr_[vb] + pti_[va]*pti_[vb];
        float doti = ptr_[va]*pti_[vb] - pti_[va]*ptr_[vb];
        P2[tb][va][vb] = 2.f * LOG2E * (dotr*gr2[tb] - doti*gi2[tb]);
    }
    __syncthreads();   // 3

    // ---------------- iteration-invariant per-thread pieces ----------------
    const float Kpart = u2s + G2[2][i2] + G2[3][i3] + P2[5][i2][i3];
    float Rp[16];
#pragma unroll
    for (int s = 0; s < 16; ++s)
        Rp[s] = G2[1][s] + P2[3][s][i2] + P2[4][s][i3];

    // ---------------- 2 chunk-iterations ----------------
    for (int it = 0; it < 2; ++it) {
        const int chunk = g * 2 + it;
        const float Kit = Kpart + G2[0][chunk] + P2[1][chunk][i2] + P2[2][chunk][i3];
        float xl[16];
        float vmA = -3.4e38f;
#pragma unroll
        for (int s = 0; s < 16; ++s) {
            float x = -(Kit + Rp[s] + P2[0][chunk][s]);
            xl[s] = x;
            vmA = fmaxf(vmA, x);
            xbuf[s][t] = x;
        }
        pmax[t] = vmA;
        __syncthreads();   // 4

        // 2a: row-cluster maxes (j1) + M2/M3
        {
            float m = -3.4e38f;
#pragma unroll
            for (int j = 0; j < 16; ++j) m = fmaxf(m, xbuf[i3][i2*16 + ((j + i3) & 15)]);
            cm[i3][i2] = m;
        }
        if (t < 16) {
            float m = -3.4e38f;
#pragma unroll
            for (int j = 0; j < 16; ++j) m = fmaxf(m, pmax[t*16 + ((j + t) & 15)]);
            m2b[t] = m;
        } else if (t < 32) {
            const int d = t - 16;
            float m = -3.4e38f;
#pragma unroll
            for (int j = 0; j < 16; ++j) m = fmaxf(m, pmax[d + 16*((j + d) & 15)]);
            m3b[d] = m;
        }
        __syncthreads();   // 5

        // 2b: M1; shared-exp j2/j3 partials
        if (t < 16) {
            float m = -3.4e38f;
#pragma unroll
            for (int j = 0; j < 16; ++j) m = fmaxf(m, cm[t][j]);
            m1b[t] = m;
        }
        const float M2 = m2b[i2], M3 = m3b[i3];
        const float Mlo = fminf(M2, M3);
        float acc = 0.f;
#pragma unroll
        for (int s = 0; s < 16; ++s) acc += EXP2(xl[s] - Mlo);
        part2[t] = acc * EXP2(Mlo - M2);
        part3[t] = acc * EXP2(Mlo - M3);
        __syncthreads();   // 6

        // 2c: j1 exp-sums; j2/j3 group sums -> pairs (agent-scope stores)
        {
            const float M1 = m1b[i3];
            float ssum = 0.f;
#pragma unroll
            for (int j = 0; j < 16; ++j)
                ssum += EXP2(xbuf[i3][i2*16 + ((j + i3) & 15)] - M1);
            cm[i3][i2] = ssum;
        }
        if (t < 16) {
            float S2 = 0.f;
#pragma unroll
            for (int j = 0; j < 16; ++j) S2 += part2[t*16 + ((j + t) & 15)];
            s2b[t] = S2;
            float* w = pairs + ((b*48 + 16 + t)*16 + chunk)*2;
            __hip_atomic_store(&w[0], m2b[t], __ATOMIC_RELAXED, __HIP_MEMORY_SCOPE_AGENT);
            __hip_atomic_store(&w[1], S2,     __ATOMIC_RELAXED, __HIP_MEMORY_SCOPE_AGENT);
        } else if (t < 32) {
            const int d = t - 16;
            float S3 = 0.f;
#pragma unroll
            for (int j = 0; j < 16; ++j) S3 += part3[d + 16*((j + d) & 15)];
            float* w = pairs + ((b*48 + 32 + d)*16 + chunk)*2;
            __hip_atomic_store(&w[0], m3b[d], __ATOMIC_RELAXED, __HIP_MEMORY_SCOPE_AGENT);
            __hip_atomic_store(&w[1], S3,     __ATOMIC_RELAXED, __HIP_MEMORY_SCOPE_AGENT);
        }
        __syncthreads();   // 7

        // j1 pairs + j0 finalize
        if (t < 16) {
            float S1 = 0.f;
#pragma unroll
            for (int j = 0; j < 16; ++j) S1 += cm[t][j];
            float* w = pairs + ((b*48 + t)*16 + chunk)*2;
            __hip_atomic_store(&w[0], m1b[t], __ATOMIC_RELAXED, __HIP_MEMORY_SCOPE_AGENT);
            __hip_atomic_store(&w[1], S1,     __ATOMIC_RELAXED, __HIP_MEMORY_SCOPE_AGENT);
        }
        if (t == 16) {
            float M0 = m2b[0];
#pragma unroll
            for (int i = 1; i < 16; ++i) M0 = fmaxf(M0, m2b[i]);
            float S0 = 0.f;
#pragma unroll
            for (int i = 0; i < 16; ++i) S0 += s2b[i] * EXP2(m2b[i] - M0);
            out[b*64 + chunk] = LN2 * (LOG2(S0) + M0);
        }
        __syncthreads();   // 8: drains vmcnt(0); also guards xbuf reuse next it
    }

    // ---------------- flag publish + merger (g==7, wave0 only) ----------------
    if (t == 0)
        __hip_atomic_store(&flags[b*8 + g], MAGIC, __ATOMIC_RELAXED,
                           __HIP_MEMORY_SCOPE_AGENT);
    if (g == 7 && t < 64) {
        for (;;) {
            int ok = (t >= 8) ||
                (__hip_atomic_load(&flags[b*8 + t], __ATOMIC_RELAXED,
                                   __HIP_MEMORY_SCOPE_AGENT) == MAGIC);
            if (__all(ok)) break;
            __builtin_amdgcn_s_sleep(1);
        }
        if (t < 48) {
            const float* p = pairs + ((b*48 + t)*16)*2;
            float Mv[16], Sv[16];
            float M = -3.4e38f;
#pragma unroll
            for (int i = 0; i < 16; ++i) {
                Mv[i] = __hip_atomic_load(&p[2*i],   __ATOMIC_RELAXED, __HIP_MEMORY_SCOPE_AGENT);
                Sv[i] = __hip_atomic_load(&p[2*i+1], __ATOMIC_RELAXED, __HIP_MEMORY_SCOPE_AGENT);
                M = fmaxf(M, Mv[i]);
            }
            float S = 0.f;
#pragma unroll
            for (int i = 0; i < 16; ++i) S += Sv[i] * EXP2(Mv[i] - M);
            out[b*64 + 16 + t] = LN2 * (LOG2(S) + M);
        }
    }
}

extern "C" void kernel_launch(void* const* d_in, const int* in_sizes, int n_in,
                              void* d_out, int out_size, void* d_ws, size_t ws_size,
                              hipStream_t stream) {
    const float* yr = (const float*)d_in[0];
    const float* yi = (const float*)d_in[1];
    const float* hr = (const float*)d_in[2];
    const float* hi = (const float*)d_in[3];
    const float* sr = (const float*)d_in[4];
    const float* si = (const float*)d_in[5];
    const float* vr = (const float*)d_in[6];
    const float* vi = (const float*)d_in[7];
    float* pairs = (float*)d_ws;                       // [64][48][16][2] floats
    unsigned* flags = (unsigned*)d_ws + 64*48*16*2;    // 512 uints after pairs
    float* out = (float*)d_out;
    hipLaunchKernelGGL(k_fused, dim3(512), dim3(256), 0, stream,
                       yr, yi, hr, hi, sr, si, vr, vi, flags, pairs, out);
}